// Round 6
// baseline (237.954 us; speedup 1.0000x reference)
//
#include <hip/hip_runtime.h>

#define NDF 96            // feature dim
#define NCB 3             // column blocks of 32 feats (64B bf16) each
#define NQ  4             // u16x8 (16B) chunks per column block (32/8)
#define NCHB 12           // u16x8 chunks per full row (96/8)

typedef unsigned short u16x8 __attribute__((ext_vector_type(8)));

__device__ __forceinline__ float bf2f(unsigned short u) {
    union { unsigned int i; float f; } x;
    x.i = ((unsigned int)u) << 16;
    return x.f;
}
__device__ __forceinline__ unsigned short f2bf(float f) {
    union { float f; unsigned int i; } x;
    x.f = f;
    unsigned int i = x.i;
    return (unsigned short)((i + 0x7FFFu + ((i >> 16) & 1u)) >> 16);  // RNE
}

// ---------------- CSR build ----------------

__global__ void k_zero(int* __restrict__ deg, int n) {
    int i = blockIdx.x * blockDim.x + threadIdx.x;
    if (i < n) deg[i] = 0;
}

__global__ void k_count(const int* __restrict__ dst, int E, int* __restrict__ deg) {
    int e = blockIdx.x * blockDim.x + threadIdx.x;
    if (e < E) atomicAdd(&deg[dst[e]], 1);
}

// Block-local exclusive scan: row_ptr[i] = local exclusive prefix within this
// 1024-chunk; blk_sums[blockIdx] = chunk total.
__global__ void __launch_bounds__(1024) k_scan_blk(const int* __restrict__ deg, int n,
                                                   int* __restrict__ row_ptr,
                                                   int* __restrict__ blk_sums) {
    __shared__ int wsum[16];
    int tid  = threadIdx.x;
    int lane = tid & 63;
    int wid  = tid >> 6;
    int i = blockIdx.x * 1024 + tid;
    int x = (i < n) ? deg[i] : 0;
    int val = x;
    #pragma unroll
    for (int off = 1; off < 64; off <<= 1) {
        int t = __shfl_up(val, off, 64);
        if (lane >= off) val += t;
    }
    if (lane == 63) wsum[wid] = val;
    __syncthreads();
    if (wid == 0) {
        int w = (lane < 16) ? wsum[lane] : 0;
        #pragma unroll
        for (int off = 1; off < 16; off <<= 1) {
            int t = __shfl_up(w, off, 64);
            if (lane >= off) w += t;
        }
        if (lane < 16) wsum[lane] = w;   // inclusive per-wave prefix sums
    }
    __syncthreads();
    int wave_off = (wid > 0) ? wsum[wid - 1] : 0;
    if (i < n) row_ptr[i] = val + wave_off - x;     // local exclusive
    if (tid == 0) blk_sums[blockIdx.x] = wsum[15];  // chunk total
}

// Single-wave exclusive scan of block sums.
__global__ void __launch_bounds__(64) k_scan_top(const int* __restrict__ blk_sums,
                                                 int* __restrict__ blk_off, int nblk) {
    int lane = threadIdx.x;
    int carry = 0;
    for (int base = 0; base < nblk; base += 64) {
        int i = base + lane;
        int x = (i < nblk) ? blk_sums[i] : 0;
        int val = x;
        #pragma unroll
        for (int off = 1; off < 64; off <<= 1) {
            int t = __shfl_up(val, off, 64);
            if (lane >= off) val += t;
        }
        if (i < nblk) blk_off[i] = carry + val - x;
        carry += __shfl(val, 63, 64);
    }
}

// Fused: finalize row_ptr (+block offset), init cursor copy, compute norms.
__global__ void k_finish(const int* __restrict__ deg, const int* __restrict__ blk_off,
                         int* __restrict__ row_ptr, int* __restrict__ cursor,
                         float* __restrict__ ds, float* __restrict__ dinv,
                         int n, int E) {
    int i = blockIdx.x * blockDim.x + threadIdx.x;
    if (i < n) {
        int val = row_ptr[i] + blk_off[i >> 10];
        row_ptr[i] = val;
        cursor[i]  = val;
        float d = (float)deg[i];          // deg >= 1 (self-loops)
        ds[i]   = rsqrtf(d);
        dinv[i] = 1.0f / d;
    }
    if (i == 0) row_ptr[n] = E;
}

__global__ void k_fill(const int* __restrict__ src, const int* __restrict__ dst, int E,
                       int* __restrict__ cursor, unsigned short* __restrict__ csr_src) {
    int e = blockIdx.x * blockDim.x + threadIdx.x;
    if (e < E) {
        int p = atomicAdd(&cursor[dst[e]], 1);   // cursor starts at row_ptr[d]
        csr_src[p] = (unsigned short)src[e];     // src < 65536
    }
}

// ---------------- feature pipeline ----------------
// Planar layout: hs[cb][v][32] bf16 — plane cb is a contiguous n*64B slab.
// u16x8 index of (cb, v, q) = (cb*n + v)*NQ + q.

// hs0 = bf16(F * d^{-1/2}),  hinit = bf16(F * d^{-1})   (both planar)
__global__ void __launch_bounds__(256) k_scale(
        const float* __restrict__ feat, const float* __restrict__ ds,
        const float* __restrict__ dinv, unsigned short* __restrict__ hs,
        unsigned short* __restrict__ hinit, int n, int nt /* = n*NCHB */) {
    int t = blockIdx.x * blockDim.x + threadIdx.x;
    if (t >= nt) return;
    int v = t / NCHB;
    int c = t - v * NCHB;          // 0..11
    int cb = c >> 2;
    int q  = c & 3;
    const float4* f4 = (const float4*)feat;
    float4 fa = f4[t * 2];
    float4 fb = f4[t * 2 + 1];
    float s  = ds[v];
    float iv = dinv[v];
    u16x8 o, oi;
    o[0] = f2bf(fa.x * s);  oi[0] = f2bf(fa.x * iv);
    o[1] = f2bf(fa.y * s);  oi[1] = f2bf(fa.y * iv);
    o[2] = f2bf(fa.z * s);  oi[2] = f2bf(fa.z * iv);
    o[3] = f2bf(fa.w * s);  oi[3] = f2bf(fa.w * iv);
    o[4] = f2bf(fb.x * s);  oi[4] = f2bf(fb.x * iv);
    o[5] = f2bf(fb.y * s);  oi[5] = f2bf(fb.y * iv);
    o[6] = f2bf(fb.z * s);  oi[6] = f2bf(fb.z * iv);
    o[7] = f2bf(fb.w * s);  oi[7] = f2bf(fb.w * iv);
    int pidx = (cb * n + v) * NQ + q;
    ((u16x8*)hs)[pidx]    = o;
    ((u16x8*)hinit)[pidx] = oi;
}

// One propagation round, column-blocked. Thread t (cb-major):
//   cb = t/(n*4); v = (t%(n*4))>>2; q = t&3.
// Each neighbor gather touches exactly one 64B line of plane cb (hot set
// ~3.2MB -> per-XCD L2 resident while that cb's block range executes).
//   h_new = (sum_s hs[cb][s]) * ds[v] + hinit[cb][v]
//   LAST=0: write bf16(h_new * ds[v]) planar;  LAST=1: write fp32 row-major.
template <int LAST>
__global__ void __launch_bounds__(256) k_prop(
        const unsigned short* __restrict__ hs, const int* __restrict__ row_ptr,
        const unsigned short* __restrict__ csr_src, const float* __restrict__ ds,
        const unsigned short* __restrict__ hinit,
        void* __restrict__ outp, int n, int n4 /* = n*NQ */) {
    int t = blockIdx.x * blockDim.x + threadIdx.x;
    if (t >= NCB * n4) return;
    int cb = t / n4;
    int r  = t - cb * n4;
    int v  = r >> 2;
    int q  = r & 3;
    int beg = row_ptr[v];
    int end = row_ptr[v + 1];
    // per-thread plane base: hs8 + cb*n*4 + q; neighbor s contributes at s*4
    const u16x8* __restrict__ hs8 = (const u16x8*)hs + (size_t)cb * n4 + q;
    float a0 = 0.f, a1 = 0.f, a2 = 0.f, a3 = 0.f;
    float a4 = 0.f, a5 = 0.f, a6 = 0.f, a7 = 0.f;
    for (int j = beg; j < end; ++j) {
        int s = (int)csr_src[j];            // same addr across the node's 4 lanes
        u16x8 hv = hs8[s * NQ];             // 16B of one 64B line of plane cb
        a0 += bf2f(hv[0]); a1 += bf2f(hv[1]);
        a2 += bf2f(hv[2]); a3 += bf2f(hv[3]);
        a4 += bf2f(hv[4]); a5 += bf2f(hv[5]);
        a6 += bf2f(hv[6]); a7 += bf2f(hv[7]);
    }
    float sv = ds[v];
    int pidx = (cb * n + v) * NQ + q;
    u16x8 hi = ((const u16x8*)hinit)[pidx];
    float r0 = a0 * sv + bf2f(hi[0]);
    float r1 = a1 * sv + bf2f(hi[1]);
    float r2 = a2 * sv + bf2f(hi[2]);
    float r3 = a3 * sv + bf2f(hi[3]);
    float r4 = a4 * sv + bf2f(hi[4]);
    float r5 = a5 * sv + bf2f(hi[5]);
    float r6 = a6 * sv + bf2f(hi[6]);
    float r7 = a7 * sv + bf2f(hi[7]);
    if (LAST) {
        // fp32 row-major: floats [v*96 + cb*32 + q*8 .. +8)
        float4* o4 = (float4*)outp;
        int fidx = v * 24 + cb * 8 + q * 2;   // float4 units
        o4[fidx]     = make_float4(r0, r1, r2, r3);
        o4[fidx + 1] = make_float4(r4, r5, r6, r7);
    } else {
        u16x8 o;
        o[0] = f2bf(r0 * sv); o[1] = f2bf(r1 * sv);
        o[2] = f2bf(r2 * sv); o[3] = f2bf(r3 * sv);
        o[4] = f2bf(r4 * sv); o[5] = f2bf(r5 * sv);
        o[6] = f2bf(r6 * sv); o[7] = f2bf(r7 * sv);
        ((u16x8*)outp)[pidx] = o;
    }
}

// ---------------- launch ----------------

extern "C" void kernel_launch(void* const* d_in, const int* in_sizes, int n_in,
                              void* d_out, int out_size, void* d_ws, size_t ws_size,
                              hipStream_t stream) {
    const int*   src  = (const int*)d_in[0];
    const int*   dst  = (const int*)d_in[1];
    const float* feat = (const float*)d_in[2];
    const int E = in_sizes[0];
    const int n = in_sizes[2] / NDF;
    float* out = (float*)d_out;

    // workspace carve-up (256B aligned)
    char* p = (char*)d_ws;
    auto take = [&](size_t bytes) {
        char* r = p;
        p += (bytes + 255) & ~size_t(255);
        return r;
    };
    const int nblk = (n + 1023) / 1024;
    int*   deg      = (int*)  take((size_t)n * 4);
    int*   cursor   = (int*)  take((size_t)n * 4);
    int*   row_ptr  = (int*)  take((size_t)(n + 1) * 4);
    int*   blk_sums = (int*)  take((size_t)nblk * 4);
    int*   blk_off  = (int*)  take((size_t)nblk * 4);
    float* dsn      = (float*)take((size_t)n * 4);
    float* dinvn    = (float*)take((size_t)n * 4);
    unsigned short* csr   = (unsigned short*)take((size_t)E * 2);
    unsigned short* hsA   = (unsigned short*)take((size_t)n * NDF * 2);
    unsigned short* hsB   = (unsigned short*)take((size_t)n * NDF * 2);
    unsigned short* hinit = (unsigned short*)take((size_t)n * NDF * 2);
    (void)ws_size;

    const int nt  = n * NCHB;          // u16x8 chunks in a feature matrix
    const int n4  = n * NQ;
    const int bN  = (n  + 255) / 256;
    const int bE  = (E  + 255) / 256;
    const int bT  = (nt + 255) / 256;  // nt == NCB*n4

    // CSR build (redone every call; deterministic work)
    k_zero    <<<bN, 256, 0, stream>>>(deg, n);
    k_count   <<<bE, 256, 0, stream>>>(dst, E, deg);
    k_scan_blk<<<nblk, 1024, 0, stream>>>(deg, n, row_ptr, blk_sums);
    k_scan_top<<<1, 64, 0, stream>>>(blk_sums, blk_off, nblk);
    k_finish  <<<bN, 256, 0, stream>>>(deg, blk_off, row_ptr, cursor, dsn, dinvn, n, E);
    k_fill    <<<bE, 256, 0, stream>>>(src, dst, E, cursor, csr);

    // hs0 = bf16(F * d^-1/2), hinit = bf16(F * d^-1)  (planar [cb][v][32])
    k_scale<<<bT, 256, 0, stream>>>(feat, dsn, dinvn, hsA, hinit, n, nt);

    // K = 3 propagation rounds (ping-pong hsA/hsB, final round writes d_out)
    k_prop<0><<<bT, 256, 0, stream>>>(hsA, row_ptr, csr, dsn, hinit, hsB, n, n4);
    k_prop<0><<<bT, 256, 0, stream>>>(hsB, row_ptr, csr, dsn, hinit, hsA, n, n4);
    k_prop<1><<<bT, 256, 0, stream>>>(hsA, row_ptr, csr, dsn, hinit, out, n, n4);
}

// Round 7
// 180.783 us; speedup vs baseline: 1.3162x; 1.3162x over previous
//
#include <hip/hip_runtime.h>

#define NDF 96            // feature dim
#define NCHB 12           // u16x8 (8-feat, 16B) chunks per bf16 feature row (96/8)

typedef unsigned short u16x8 __attribute__((ext_vector_type(8)));

__device__ __forceinline__ float bf2f(unsigned short u) {
    union { unsigned int i; float f; } x;
    x.i = ((unsigned int)u) << 16;
    return x.f;
}
__device__ __forceinline__ unsigned short f2bf(float f) {
    union { float f; unsigned int i; } x;
    x.f = f;
    unsigned int i = x.i;
    return (unsigned short)((i + 0x7FFFu + ((i >> 16) & 1u)) >> 16);  // RNE
}

// ---------------- CSR build ----------------

__global__ void k_zero(int* __restrict__ deg, int n) {
    int i = blockIdx.x * blockDim.x + threadIdx.x;
    if (i < n) deg[i] = 0;
}

__global__ void k_count(const int* __restrict__ dst, int E, int* __restrict__ deg) {
    int e = blockIdx.x * blockDim.x + threadIdx.x;
    if (e < E) atomicAdd(&deg[dst[e]], 1);
}

// Block-local exclusive scan: row_ptr[i] = local exclusive prefix within this
// 1024-chunk; blk_sums[blockIdx] = chunk total.
__global__ void __launch_bounds__(1024) k_scan_blk(const int* __restrict__ deg, int n,
                                                   int* __restrict__ row_ptr,
                                                   int* __restrict__ blk_sums) {
    __shared__ int wsum[16];
    int tid  = threadIdx.x;
    int lane = tid & 63;
    int wid  = tid >> 6;
    int i = blockIdx.x * 1024 + tid;
    int x = (i < n) ? deg[i] : 0;
    int val = x;
    #pragma unroll
    for (int off = 1; off < 64; off <<= 1) {
        int t = __shfl_up(val, off, 64);
        if (lane >= off) val += t;
    }
    if (lane == 63) wsum[wid] = val;
    __syncthreads();
    if (wid == 0) {
        int w = (lane < 16) ? wsum[lane] : 0;
        #pragma unroll
        for (int off = 1; off < 16; off <<= 1) {
            int t = __shfl_up(w, off, 64);
            if (lane >= off) w += t;
        }
        if (lane < 16) wsum[lane] = w;   // inclusive per-wave prefix sums
    }
    __syncthreads();
    int wave_off = (wid > 0) ? wsum[wid - 1] : 0;
    if (i < n) row_ptr[i] = val + wave_off - x;     // local exclusive
    if (tid == 0) blk_sums[blockIdx.x] = wsum[15];  // chunk total
}

// Single-wave exclusive scan of block sums.
__global__ void __launch_bounds__(64) k_scan_top(const int* __restrict__ blk_sums,
                                                 int* __restrict__ blk_off, int nblk) {
    int lane = threadIdx.x;
    int carry = 0;
    for (int base = 0; base < nblk; base += 64) {
        int i = base + lane;
        int x = (i < nblk) ? blk_sums[i] : 0;
        int val = x;
        #pragma unroll
        for (int off = 1; off < 64; off <<= 1) {
            int t = __shfl_up(val, off, 64);
            if (lane >= off) val += t;
        }
        if (i < nblk) blk_off[i] = carry + val - x;
        carry += __shfl(val, 63, 64);
    }
}

// Fused: finalize row_ptr (+block offset), init cursor copy, compute norms.
__global__ void k_finish(const int* __restrict__ deg, const int* __restrict__ blk_off,
                         int* __restrict__ row_ptr, int* __restrict__ cursor,
                         float* __restrict__ ds, float* __restrict__ dinv,
                         int n, int E) {
    int i = blockIdx.x * blockDim.x + threadIdx.x;
    if (i < n) {
        int val = row_ptr[i] + blk_off[i >> 10];
        row_ptr[i] = val;
        cursor[i]  = val;
        float d = (float)deg[i];          // deg >= 1 (self-loops)
        ds[i]   = rsqrtf(d);
        dinv[i] = 1.0f / d;
    }
    if (i == 0) row_ptr[n] = E;
}

__global__ void k_fill(const int* __restrict__ src, const int* __restrict__ dst, int E,
                       int* __restrict__ cursor, unsigned short* __restrict__ csr_src) {
    int e = blockIdx.x * blockDim.x + threadIdx.x;
    if (e < E) {
        int p = atomicAdd(&cursor[dst[e]], 1);   // cursor starts at row_ptr[d]
        csr_src[p] = (unsigned short)src[e];     // src < 65536
    }
}

// ---------------- feature pipeline ----------------
// Row-major bf16: hs[v][96], u16x8 chunk index = v*NCHB + c.

// hs0 = bf16(F * d^{-1/2}),  hinit = bf16(F * d^{-1})
__global__ void __launch_bounds__(256) k_scale(
        const float* __restrict__ feat, const float* __restrict__ ds,
        const float* __restrict__ dinv, unsigned short* __restrict__ hs,
        unsigned short* __restrict__ hinit, int nt /* = n*NCHB */) {
    int t = blockIdx.x * blockDim.x + threadIdx.x;
    if (t >= nt) return;
    int v = t / NCHB;
    const float4* f4 = (const float4*)feat;
    float4 fa = f4[t * 2];
    float4 fb = f4[t * 2 + 1];
    float s  = ds[v];
    float iv = dinv[v];
    u16x8 o, oi;
    o[0] = f2bf(fa.x * s);  oi[0] = f2bf(fa.x * iv);
    o[1] = f2bf(fa.y * s);  oi[1] = f2bf(fa.y * iv);
    o[2] = f2bf(fa.z * s);  oi[2] = f2bf(fa.z * iv);
    o[3] = f2bf(fa.w * s);  oi[3] = f2bf(fa.w * iv);
    o[4] = f2bf(fb.x * s);  oi[4] = f2bf(fb.x * iv);
    o[5] = f2bf(fb.y * s);  oi[5] = f2bf(fb.y * iv);
    o[6] = f2bf(fb.z * s);  oi[6] = f2bf(fb.z * iv);
    o[7] = f2bf(fb.w * s);  oi[7] = f2bf(fb.w * iv);
    ((u16x8*)hs)[t]    = o;
    ((u16x8*)hinit)[t] = oi;
}

// One propagation round. Thread = (node v, 8-feat chunk c). Inner gather loop
// unrolled 8/4/2/1-deep so up to 8 independent 16B gathers are in flight per
// lane (latency-concurrency was the bound at 1-deep: VALUBusy 13%, 2.6 TB/s).
//   h_new = (sum_{s in N(v)} hs[s]) * ds[v] + hinit[v]
//   LAST=0: write bf16(h_new * ds[v]);  LAST=1: write fp32 h_new.
template <int LAST>
__global__ void __launch_bounds__(256) k_prop(
        const unsigned short* __restrict__ hs, const int* __restrict__ row_ptr,
        const unsigned short* __restrict__ csr_src, const float* __restrict__ ds,
        const unsigned short* __restrict__ hinit,
        void* __restrict__ outp, int nt /* = n*NCHB */) {
    int t = blockIdx.x * blockDim.x + threadIdx.x;
    if (t >= nt) return;
    int v = t / NCHB;
    int c = t - v * NCHB;
    int beg = row_ptr[v];
    int end = row_ptr[v + 1];
    const u16x8* __restrict__ hs8 = (const u16x8*)hs;
    float a0 = 0.f, a1 = 0.f, a2 = 0.f, a3 = 0.f;
    float a4 = 0.f, a5 = 0.f, a6 = 0.f, a7 = 0.f;

    #define ACC(HV) do { \
        a0 += bf2f((HV)[0]); a1 += bf2f((HV)[1]); \
        a2 += bf2f((HV)[2]); a3 += bf2f((HV)[3]); \
        a4 += bf2f((HV)[4]); a5 += bf2f((HV)[5]); \
        a6 += bf2f((HV)[6]); a7 += bf2f((HV)[7]); } while (0)

    int j = beg;
    while (j + 8 <= end) {
        int s0 = (int)csr_src[j    ], s1 = (int)csr_src[j + 1];
        int s2 = (int)csr_src[j + 2], s3 = (int)csr_src[j + 3];
        int s4 = (int)csr_src[j + 4], s5 = (int)csr_src[j + 5];
        int s6 = (int)csr_src[j + 6], s7 = (int)csr_src[j + 7];
        u16x8 h0 = hs8[s0 * NCHB + c];
        u16x8 h1 = hs8[s1 * NCHB + c];
        u16x8 h2 = hs8[s2 * NCHB + c];
        u16x8 h3 = hs8[s3 * NCHB + c];
        u16x8 h4 = hs8[s4 * NCHB + c];
        u16x8 h5 = hs8[s5 * NCHB + c];
        u16x8 h6 = hs8[s6 * NCHB + c];
        u16x8 h7 = hs8[s7 * NCHB + c];
        ACC(h0); ACC(h1); ACC(h2); ACC(h3);
        ACC(h4); ACC(h5); ACC(h6); ACC(h7);
        j += 8;
    }
    if (j + 4 <= end) {
        int s0 = (int)csr_src[j    ], s1 = (int)csr_src[j + 1];
        int s2 = (int)csr_src[j + 2], s3 = (int)csr_src[j + 3];
        u16x8 h0 = hs8[s0 * NCHB + c];
        u16x8 h1 = hs8[s1 * NCHB + c];
        u16x8 h2 = hs8[s2 * NCHB + c];
        u16x8 h3 = hs8[s3 * NCHB + c];
        ACC(h0); ACC(h1); ACC(h2); ACC(h3);
        j += 4;
    }
    if (j + 2 <= end) {
        int s0 = (int)csr_src[j], s1 = (int)csr_src[j + 1];
        u16x8 h0 = hs8[s0 * NCHB + c];
        u16x8 h1 = hs8[s1 * NCHB + c];
        ACC(h0); ACC(h1);
        j += 2;
    }
    if (j < end) {
        int s0 = (int)csr_src[j];
        u16x8 h0 = hs8[s0 * NCHB + c];
        ACC(h0);
    }
    #undef ACC

    float sv = ds[v];
    u16x8 hi = ((const u16x8*)hinit)[t];
    float r0 = a0 * sv + bf2f(hi[0]);
    float r1 = a1 * sv + bf2f(hi[1]);
    float r2 = a2 * sv + bf2f(hi[2]);
    float r3 = a3 * sv + bf2f(hi[3]);
    float r4 = a4 * sv + bf2f(hi[4]);
    float r5 = a5 * sv + bf2f(hi[5]);
    float r6 = a6 * sv + bf2f(hi[6]);
    float r7 = a7 * sv + bf2f(hi[7]);
    if (LAST) {
        float4* o4 = (float4*)outp;
        o4[t * 2]     = make_float4(r0, r1, r2, r3);
        o4[t * 2 + 1] = make_float4(r4, r5, r6, r7);
    } else {
        u16x8 o;
        o[0] = f2bf(r0 * sv); o[1] = f2bf(r1 * sv);
        o[2] = f2bf(r2 * sv); o[3] = f2bf(r3 * sv);
        o[4] = f2bf(r4 * sv); o[5] = f2bf(r5 * sv);
        o[6] = f2bf(r6 * sv); o[7] = f2bf(r7 * sv);
        ((u16x8*)outp)[t] = o;
    }
}

// ---------------- launch ----------------

extern "C" void kernel_launch(void* const* d_in, const int* in_sizes, int n_in,
                              void* d_out, int out_size, void* d_ws, size_t ws_size,
                              hipStream_t stream) {
    const int*   src  = (const int*)d_in[0];
    const int*   dst  = (const int*)d_in[1];
    const float* feat = (const float*)d_in[2];
    const int E = in_sizes[0];
    const int n = in_sizes[2] / NDF;
    float* out = (float*)d_out;

    // workspace carve-up (256B aligned)
    char* p = (char*)d_ws;
    auto take = [&](size_t bytes) {
        char* r = p;
        p += (bytes + 255) & ~size_t(255);
        return r;
    };
    const int nblk = (n + 1023) / 1024;
    int*   deg      = (int*)  take((size_t)n * 4);
    int*   cursor   = (int*)  take((size_t)n * 4);
    int*   row_ptr  = (int*)  take((size_t)(n + 1) * 4);
    int*   blk_sums = (int*)  take((size_t)nblk * 4);
    int*   blk_off  = (int*)  take((size_t)nblk * 4);
    float* dsn      = (float*)take((size_t)n * 4);
    float* dinvn    = (float*)take((size_t)n * 4);
    unsigned short* csr   = (unsigned short*)take((size_t)E * 2);
    unsigned short* hsA   = (unsigned short*)take((size_t)n * NDF * 2);
    unsigned short* hsB   = (unsigned short*)take((size_t)n * NDF * 2);
    unsigned short* hinit = (unsigned short*)take((size_t)n * NDF * 2);
    (void)ws_size;

    const int nt  = n * NCHB;          // u16x8 chunks in a feature matrix
    const int bN  = (n  + 255) / 256;
    const int bE  = (E  + 255) / 256;
    const int bT  = (nt + 255) / 256;

    // CSR build (redone every call; deterministic work)
    k_zero    <<<bN, 256, 0, stream>>>(deg, n);
    k_count   <<<bE, 256, 0, stream>>>(dst, E, deg);
    k_scan_blk<<<nblk, 1024, 0, stream>>>(deg, n, row_ptr, blk_sums);
    k_scan_top<<<1, 64, 0, stream>>>(blk_sums, blk_off, nblk);
    k_finish  <<<bN, 256, 0, stream>>>(deg, blk_off, row_ptr, cursor, dsn, dinvn, n, E);
    k_fill    <<<bE, 256, 0, stream>>>(src, dst, E, cursor, csr);

    // hs0 = bf16(F * d^-1/2), hinit = bf16(F * d^-1)
    k_scale<<<bT, 256, 0, stream>>>(feat, dsn, dinvn, hsA, hinit, nt);

    // K = 3 propagation rounds (ping-pong hsA/hsB, final round writes d_out)
    k_prop<0><<<bT, 256, 0, stream>>>(hsA, row_ptr, csr, dsn, hinit, hsB, nt);
    k_prop<0><<<bT, 256, 0, stream>>>(hsB, row_ptr, csr, dsn, hinit, hsA, nt);
    k_prop<1><<<bT, 256, 0, stream>>>(hsA, row_ptr, csr, dsn, hinit, out, nt);
}

// Round 8
// 119.875 us; speedup vs baseline: 1.9850x; 1.5081x over previous
//
#include <hip/hip_runtime.h>

#define NDF 96            // feature dim
#define NCHB 12           // u16x8 (8-feat, 16B) chunks per bf16 feature row (96/8)
#define BSH 8             // 256 nodes per dst-bucket
#define BCAP 8192         // bucket capacity (u32 entries, power of 2; max ~4700 used)
#define TILE 4096         // edges per passA block

typedef unsigned short u16x8 __attribute__((ext_vector_type(8)));

__device__ __forceinline__ float bf2f(unsigned short u) {
    union { unsigned int i; float f; } x;
    x.i = ((unsigned int)u) << 16;
    return x.f;
}
__device__ __forceinline__ unsigned short f2bf(float f) {
    union { float f; unsigned int i; } x;
    x.f = f;
    unsigned int i = x.i;
    return (unsigned short)((i + 0x7FFFu + ((i >> 16) & 1u)) >> 16);  // RNE
}

// ---------------- CSR build (bucketed, LDS-staged) ----------------

__global__ void k_binit(int* __restrict__ bcount) {
    bcount[threadIdx.x] = 0;          // 256 threads, 1 block
}

// Pass A: partition random edges into 196 dst-buckets. Per block: LDS
// histogram -> LDS scan -> global per-bucket reservation -> LDS staging in
// bucket-grouped order -> coalesced bulk write of (dst<<16|src) u32 entries.
__global__ void __launch_bounds__(512) k_passA(
        const int* __restrict__ src, const int* __restrict__ dst, int nr,
        int* __restrict__ bcount, unsigned int* __restrict__ bucket) {
    __shared__ unsigned int stage[TILE];
    __shared__ int cnt[256], sstart[256], lcur[256], gbase[256];
    __shared__ int wsum4[4], pref4[4];
    int tid  = threadIdx.x;
    int tile = blockIdx.x * TILE;
    int cnt_e = min(TILE, nr - tile);
    if (tid < 256) cnt[tid] = 0;
    __syncthreads();
    for (int k = tid; k < cnt_e; k += 512)
        atomicAdd(&cnt[dst[tile + k] >> BSH], 1);
    __syncthreads();
    int x = 0, val = 0;
    if (tid < 256) {                  // 256-wide scan: 4 wave-scans + combine
        x = cnt[tid];
        val = x;
        int lane = tid & 63;
        #pragma unroll
        for (int off = 1; off < 64; off <<= 1) {
            int t = __shfl_up(val, off, 64);
            if (lane >= off) val += t;
        }
        if (lane == 63) wsum4[tid >> 6] = val;
    }
    __syncthreads();
    if (tid == 0) {
        int s = 0;
        #pragma unroll
        for (int w = 0; w < 4; ++w) { pref4[w] = s; s += wsum4[w]; }
    }
    __syncthreads();
    if (tid < 256) {
        sstart[tid] = val + pref4[tid >> 6] - x;    // exclusive block-local start
        lcur[tid]   = 0;
        gbase[tid]  = (x > 0) ? atomicAdd(&bcount[tid], x) : 0;
    }
    __syncthreads();
    for (int k = tid; k < cnt_e; k += 512) {
        int d = dst[tile + k];
        int s = src[tile + k];
        int b = d >> BSH;
        int pos = atomicAdd(&lcur[b], 1);
        stage[sstart[b] + pos] = ((unsigned int)d << 16) | (unsigned int)s;
    }
    __syncthreads();
    for (int k = tid; k < cnt_e; k += 512) {        // coalesced write-out
        unsigned int u = stage[k];
        int b = (int)(u >> 24);                     // dst>>8
        bucket[((size_t)b << 13) + gbase[b] + (k - sstart[b])] = u;
    }
}

// Pass B: per-bucket degree count via LDS atomics. rdeg = random-edge in-deg.
__global__ void __launch_bounds__(256) k_passB(
        const int* __restrict__ bcount, const unsigned int* __restrict__ bucket,
        int* __restrict__ rdeg, int n) {
    __shared__ int dl[256];
    int tid = threadIdx.x;
    int b   = blockIdx.x;
    dl[tid] = 0;
    __syncthreads();
    int cb = bcount[b];
    const unsigned int* __restrict__ bp = bucket + ((size_t)b << 13);
    for (int k = tid; k < cb; k += 256)
        atomicAdd(&dl[(bp[k] >> 16) & 255], 1);
    __syncthreads();
    int node = (b << BSH) + tid;
    if (node < n) rdeg[node] = dl[tid];
}

// Block-local exclusive scan of rdeg: row_ptr[i] = local prefix within the
// 1024-chunk; blk_sums[blockIdx] = chunk total. (blk_off applied by consumers.)
__global__ void __launch_bounds__(1024) k_scan_blk(const int* __restrict__ rdeg, int n,
                                                   int* __restrict__ row_ptr,
                                                   int* __restrict__ blk_sums) {
    __shared__ int wsum[16];
    int tid  = threadIdx.x;
    int lane = tid & 63;
    int wid  = tid >> 6;
    int i = blockIdx.x * 1024 + tid;
    int x = (i < n) ? rdeg[i] : 0;
    int val = x;
    #pragma unroll
    for (int off = 1; off < 64; off <<= 1) {
        int t = __shfl_up(val, off, 64);
        if (lane >= off) val += t;
    }
    if (lane == 63) wsum[wid] = val;
    __syncthreads();
    if (wid == 0) {
        int w = (lane < 16) ? wsum[lane] : 0;
        #pragma unroll
        for (int off = 1; off < 16; off <<= 1) {
            int t = __shfl_up(w, off, 64);
            if (lane >= off) w += t;
        }
        if (lane < 16) wsum[lane] = w;
    }
    __syncthreads();
    int wave_off = (wid > 0) ? wsum[wid - 1] : 0;
    if (i < n) row_ptr[i] = val + wave_off - x;
    if (tid == 0) blk_sums[blockIdx.x] = wsum[15];
}

// Single-wave exclusive scan of block sums.
__global__ void __launch_bounds__(64) k_scan_top(const int* __restrict__ blk_sums,
                                                 int* __restrict__ blk_off, int nblk) {
    int lane = threadIdx.x;
    int carry = 0;
    for (int base = 0; base < nblk; base += 64) {
        int i = base + lane;
        int x = (i < nblk) ? blk_sums[i] : 0;
        int val = x;
        #pragma unroll
        for (int off = 1; off < 64; off <<= 1) {
            int t = __shfl_up(val, off, 64);
            if (lane >= off) val += t;
        }
        if (i < nblk) blk_off[i] = carry + val - x;
        carry += __shfl(val, 63, 64);
    }
}

// Pass C: per-bucket CSR fill. Scatter happens in LDS (relative cursors +
// staged ushort window), then coalesced write-out to csr[base..base+total).
__global__ void __launch_bounds__(512) k_passC(
        const int* __restrict__ bcount, const unsigned int* __restrict__ bucket,
        const int* __restrict__ row_ptr, const int* __restrict__ blk_off,
        unsigned short* __restrict__ csr, int n, int nr) {
    __shared__ int cur[257];
    __shared__ unsigned short stg[BCAP];
    int tid = threadIdx.x;
    int b   = blockIdx.x;
    if (tid <= 256) {
        int node = (b << BSH) + tid;
        cur[tid] = (node >= n) ? nr : (row_ptr[node] + blk_off[node >> 10]);
    }
    __syncthreads();
    int base  = cur[0];
    int total = cur[256] - base;
    __syncthreads();                   // reads of cur done before rebase
    if (tid < 256) cur[tid] -= base;
    __syncthreads();
    int cb = bcount[b];                // == total
    const unsigned int* __restrict__ bp = bucket + ((size_t)b << 13);
    for (int k = tid; k < cb; k += 512) {
        unsigned int u = bp[k];
        int p = atomicAdd(&cur[(u >> 16) & 255], 1);
        stg[p] = (unsigned short)(u & 0xFFFFu);
    }
    __syncthreads();
    for (int k = tid; k < total; k += 512)
        csr[base + k] = stg[k];
}

// ---------------- feature pipeline ----------------
// Row-major bf16: hs[v][96], u16x8 chunk index = v*NCHB + c.

// hs0 = bf16(F * d^{-1/2}),  hinit = bf16(F * d^{-1});  d = rdeg+1 inline.
__global__ void __launch_bounds__(256) k_scale(
        const float* __restrict__ feat, const int* __restrict__ rdeg,
        unsigned short* __restrict__ hs, unsigned short* __restrict__ hinit,
        int nt /* = n*NCHB */) {
    int t = blockIdx.x * blockDim.x + threadIdx.x;
    if (t >= nt) return;
    int v = t / NCHB;
    float d  = (float)(rdeg[v] + 1);
    float s  = rsqrtf(d);
    float iv = 1.0f / d;
    const float4* f4 = (const float4*)feat;
    float4 fa = f4[t * 2];
    float4 fb = f4[t * 2 + 1];
    u16x8 o, oi;
    o[0] = f2bf(fa.x * s);  oi[0] = f2bf(fa.x * iv);
    o[1] = f2bf(fa.y * s);  oi[1] = f2bf(fa.y * iv);
    o[2] = f2bf(fa.z * s);  oi[2] = f2bf(fa.z * iv);
    o[3] = f2bf(fa.w * s);  oi[3] = f2bf(fa.w * iv);
    o[4] = f2bf(fb.x * s);  oi[4] = f2bf(fb.x * iv);
    o[5] = f2bf(fb.y * s);  oi[5] = f2bf(fb.y * iv);
    o[6] = f2bf(fb.z * s);  oi[6] = f2bf(fb.z * iv);
    o[7] = f2bf(fb.w * s);  oi[7] = f2bf(fb.w * iv);
    ((u16x8*)hs)[t]    = o;
    ((u16x8*)hinit)[t] = oi;
}

// One propagation round. Thread = (node v, 8-feat chunk c). Accumulator seeded
// with the node's own row (implicit self-loop). Gathers 8/4/2/1-deep unrolled.
//   h_new = (own + sum_{s in Nr(v)} hs[s]) * ds + hinit[v],  ds = rsqrt(rdeg+1)
//   LAST=0: write bf16(h_new * ds);  LAST=1: write fp32 h_new.
template <int LAST>
__global__ void __launch_bounds__(256) k_prop(
        const unsigned short* __restrict__ hs, const int* __restrict__ row_ptr,
        const int* __restrict__ blk_off, const unsigned short* __restrict__ csr_src,
        const int* __restrict__ rdeg, const unsigned short* __restrict__ hinit,
        void* __restrict__ outp, int n, int nr, int nt) {
    int t = blockIdx.x * blockDim.x + threadIdx.x;
    if (t >= nt) return;
    int v = t / NCHB;
    int c = t - v * NCHB;
    int beg = row_ptr[v] + blk_off[v >> 10];
    int end = (v + 1 == n) ? nr : (row_ptr[v + 1] + blk_off[(v + 1) >> 10]);
    const u16x8* __restrict__ hs8 = (const u16x8*)hs;
    u16x8 own = hs8[t];                       // self-loop contribution
    float a0 = bf2f(own[0]), a1 = bf2f(own[1]);
    float a2 = bf2f(own[2]), a3 = bf2f(own[3]);
    float a4 = bf2f(own[4]), a5 = bf2f(own[5]);
    float a6 = bf2f(own[6]), a7 = bf2f(own[7]);

    #define ACC(HV) do { \
        a0 += bf2f((HV)[0]); a1 += bf2f((HV)[1]); \
        a2 += bf2f((HV)[2]); a3 += bf2f((HV)[3]); \
        a4 += bf2f((HV)[4]); a5 += bf2f((HV)[5]); \
        a6 += bf2f((HV)[6]); a7 += bf2f((HV)[7]); } while (0)

    int j = beg;
    while (j + 8 <= end) {
        int s0 = (int)csr_src[j    ], s1 = (int)csr_src[j + 1];
        int s2 = (int)csr_src[j + 2], s3 = (int)csr_src[j + 3];
        int s4 = (int)csr_src[j + 4], s5 = (int)csr_src[j + 5];
        int s6 = (int)csr_src[j + 6], s7 = (int)csr_src[j + 7];
        u16x8 h0 = hs8[s0 * NCHB + c];
        u16x8 h1 = hs8[s1 * NCHB + c];
        u16x8 h2 = hs8[s2 * NCHB + c];
        u16x8 h3 = hs8[s3 * NCHB + c];
        u16x8 h4 = hs8[s4 * NCHB + c];
        u16x8 h5 = hs8[s5 * NCHB + c];
        u16x8 h6 = hs8[s6 * NCHB + c];
        u16x8 h7 = hs8[s7 * NCHB + c];
        ACC(h0); ACC(h1); ACC(h2); ACC(h3);
        ACC(h4); ACC(h5); ACC(h6); ACC(h7);
        j += 8;
    }
    if (j + 4 <= end) {
        int s0 = (int)csr_src[j    ], s1 = (int)csr_src[j + 1];
        int s2 = (int)csr_src[j + 2], s3 = (int)csr_src[j + 3];
        u16x8 h0 = hs8[s0 * NCHB + c];
        u16x8 h1 = hs8[s1 * NCHB + c];
        u16x8 h2 = hs8[s2 * NCHB + c];
        u16x8 h3 = hs8[s3 * NCHB + c];
        ACC(h0); ACC(h1); ACC(h2); ACC(h3);
        j += 4;
    }
    if (j + 2 <= end) {
        int s0 = (int)csr_src[j], s1 = (int)csr_src[j + 1];
        u16x8 h0 = hs8[s0 * NCHB + c];
        u16x8 h1 = hs8[s1 * NCHB + c];
        ACC(h0); ACC(h1);
        j += 2;
    }
    if (j < end) {
        int s0 = (int)csr_src[j];
        u16x8 h0 = hs8[s0 * NCHB + c];
        ACC(h0);
    }
    #undef ACC

    float sv = rsqrtf((float)(rdeg[v] + 1));
    u16x8 hi = ((const u16x8*)hinit)[t];
    float r0 = a0 * sv + bf2f(hi[0]);
    float r1 = a1 * sv + bf2f(hi[1]);
    float r2 = a2 * sv + bf2f(hi[2]);
    float r3 = a3 * sv + bf2f(hi[3]);
    float r4 = a4 * sv + bf2f(hi[4]);
    float r5 = a5 * sv + bf2f(hi[5]);
    float r6 = a6 * sv + bf2f(hi[6]);
    float r7 = a7 * sv + bf2f(hi[7]);
    if (LAST) {
        float4* o4 = (float4*)outp;
        o4[t * 2]     = make_float4(r0, r1, r2, r3);
        o4[t * 2 + 1] = make_float4(r4, r5, r6, r7);
    } else {
        u16x8 o;
        o[0] = f2bf(r0 * sv); o[1] = f2bf(r1 * sv);
        o[2] = f2bf(r2 * sv); o[3] = f2bf(r3 * sv);
        o[4] = f2bf(r4 * sv); o[5] = f2bf(r5 * sv);
        o[6] = f2bf(r6 * sv); o[7] = f2bf(r7 * sv);
        ((u16x8*)outp)[t] = o;
    }
}

// ---------------- launch ----------------

extern "C" void kernel_launch(void* const* d_in, const int* in_sizes, int n_in,
                              void* d_out, int out_size, void* d_ws, size_t ws_size,
                              hipStream_t stream) {
    const int*   src  = (const int*)d_in[0];
    const int*   dst  = (const int*)d_in[1];
    const float* feat = (const float*)d_in[2];
    const int E  = in_sizes[0];
    const int n  = in_sizes[2] / NDF;
    const int nr = E - n;              // random edges; last n entries are the
                                       // appended self-loops (handled implicitly)
    float* out = (float*)d_out;

    // workspace carve-up (256B aligned)
    char* p = (char*)d_ws;
    auto take = [&](size_t bytes) {
        char* r = p;
        p += (bytes + 255) & ~size_t(255);
        return r;
    };
    const int nblk = (n + 1023) / 1024;
    const int NBK  = (n + 255) >> 8;   // dst-buckets of 256 nodes
    int* bcount        = (int*)take(256 * 4);
    int* blk_sums      = (int*)take((size_t)nblk * 4);
    int* blk_off       = (int*)take((size_t)nblk * 4);
    int* row_ptr       = (int*)take((size_t)(n + 1) * 4);
    int* rdeg          = (int*)take((size_t)n * 4);
    unsigned int* bucket = (unsigned int*)take((size_t)256 * BCAP * 4);
    unsigned short* csr  = (unsigned short*)take((size_t)nr * 2);
    unsigned short* hsA   = (unsigned short*)take((size_t)n * NDF * 2);
    unsigned short* hsB   = (unsigned short*)take((size_t)n * NDF * 2);
    unsigned short* hinit = (unsigned short*)take((size_t)n * NDF * 2);
    (void)ws_size;

    const int nt = n * NCHB;
    const int bT = (nt + 255) / 256;
    const int bA = (nr + TILE - 1) / TILE;

    // CSR build (bucketed; redone every call, deterministic work)
    k_binit   <<<1, 256, 0, stream>>>(bcount);
    k_passA   <<<bA, 512, 0, stream>>>(src, dst, nr, bcount, bucket);
    k_passB   <<<NBK, 256, 0, stream>>>(bcount, bucket, rdeg, n);
    k_scan_blk<<<nblk, 1024, 0, stream>>>(rdeg, n, row_ptr, blk_sums);
    k_scan_top<<<1, 64, 0, stream>>>(blk_sums, blk_off, nblk);
    k_passC   <<<NBK, 512, 0, stream>>>(bcount, bucket, row_ptr, blk_off, csr, n, nr);

    // hs0 = bf16(F * d^-1/2), hinit = bf16(F * d^-1)   (needs only rdeg)
    k_scale<<<bT, 256, 0, stream>>>(feat, rdeg, hsA, hinit, nt);

    // K = 3 propagation rounds (ping-pong hsA/hsB, final round writes d_out)
    k_prop<0><<<bT, 256, 0, stream>>>(hsA, row_ptr, blk_off, csr, rdeg, hinit, hsB, n, nr, nt);
    k_prop<0><<<bT, 256, 0, stream>>>(hsB, row_ptr, blk_off, csr, rdeg, hinit, hsA, n, nr, nt);
    k_prop<1><<<bT, 256, 0, stream>>>(hsA, row_ptr, blk_off, csr, rdeg, hinit, out, n, nr, nt);
}

// Round 9
// 109.540 us; speedup vs baseline: 2.1723x; 1.0944x over previous
//
#include <hip/hip_runtime.h>

#define NDF 96            // feature dim
#define NCHB 12           // u16x8 (8-feat, 16B) chunks per bf16 feature row (96/8)
#define BSH 8             // 256 nodes per dst-bucket
#define BCAP 8192         // entries per bucket (u32 bucket slab & padded csr slab)
#define TILE 4096         // edges per passA block

typedef unsigned short u16x8 __attribute__((ext_vector_type(8)));

__device__ __forceinline__ float bf2f(unsigned short u) {
    union { unsigned int i; float f; } x;
    x.i = ((unsigned int)u) << 16;
    return x.f;
}
__device__ __forceinline__ unsigned short f2bf(float f) {
    union { float f; unsigned int i; } x;
    x.f = f;
    unsigned int i = x.i;
    return (unsigned short)((i + 0x7FFFu + ((i >> 16) & 1u)) >> 16);  // RNE
}

// ---------------- init: zero bucket counters + sentinel rows ----------------
// Sentinel row n of hsA/hsB stays zero all call (padding gathers land there).
__global__ void k_binit(int* __restrict__ bcount, unsigned short* __restrict__ hsA,
                        unsigned short* __restrict__ hsB, int n) {
    int t = threadIdx.x;
    bcount[t] = 0;
    u16x8 z = {0, 0, 0, 0, 0, 0, 0, 0};
    if (t < NCHB)            ((u16x8*)hsA)[(size_t)n * NCHB + t]        = z;
    else if (t < 2 * NCHB)   ((u16x8*)hsB)[(size_t)n * NCHB + (t - NCHB)] = z;
}

// Pass A: partition random edges into dst-buckets of 256 nodes. Per block:
// LDS histogram -> LDS scan -> global per-bucket reservation -> LDS staging
// in bucket-grouped order -> coalesced write of (dst<<16|src) u32 entries.
__global__ void __launch_bounds__(512) k_passA(
        const int* __restrict__ src, const int* __restrict__ dst, int nr,
        int* __restrict__ bcount, unsigned int* __restrict__ bucket) {
    __shared__ unsigned int stage[TILE];
    __shared__ int cnt[256], sstart[256], lcur[256], gbase[256];
    __shared__ int wsum4[4], pref4[4];
    int tid  = threadIdx.x;
    int tile = blockIdx.x * TILE;
    int cnt_e = min(TILE, nr - tile);
    if (tid < 256) cnt[tid] = 0;
    __syncthreads();
    for (int k = tid; k < cnt_e; k += 512)
        atomicAdd(&cnt[dst[tile + k] >> BSH], 1);
    __syncthreads();
    int x = 0, val = 0;
    if (tid < 256) {                  // 256-wide scan: 4 wave-scans + combine
        x = cnt[tid];
        val = x;
        int lane = tid & 63;
        #pragma unroll
        for (int off = 1; off < 64; off <<= 1) {
            int t = __shfl_up(val, off, 64);
            if (lane >= off) val += t;
        }
        if (lane == 63) wsum4[tid >> 6] = val;
    }
    __syncthreads();
    if (tid == 0) {
        int s = 0;
        #pragma unroll
        for (int w = 0; w < 4; ++w) { pref4[w] = s; s += wsum4[w]; }
    }
    __syncthreads();
    if (tid < 256) {
        sstart[tid] = val + pref4[tid >> 6] - x;    // exclusive block-local start
        lcur[tid]   = 0;
        gbase[tid]  = (x > 0) ? atomicAdd(&bcount[tid], x) : 0;
    }
    __syncthreads();
    for (int k = tid; k < cnt_e; k += 512) {
        int d = dst[tile + k];
        int s = src[tile + k];
        int b = d >> BSH;
        int pos = atomicAdd(&lcur[b], 1);
        stage[sstart[b] + pos] = ((unsigned int)d << 16) | (unsigned int)s;
    }
    __syncthreads();
    for (int k = tid; k < cnt_e; k += 512) {        // coalesced write-out
        unsigned int u = stage[k];
        int b = (int)(u >> 24);                     // dst>>8
        bucket[((size_t)b << 13) + gbase[b] + (k - sstart[b])] = u;
    }
}

// Pass BC (fused): per bucket — degree count, padded-length scan, LDS-staged
// CSR fill with sentinel padding, coalesced write-out, plus feature scaling
// (hs0 = bf16(F*d^-1/2), hinit = bf16(F*d^-1)) for this bucket's 256 nodes.
// Bucket b's csr slab starts at b<<13; every row 8-padded -> 16B-aligned rows.
__global__ void __launch_bounds__(512) k_passBC(
        const int* __restrict__ bcount, const unsigned int* __restrict__ bucket,
        const float* __restrict__ feat, int* __restrict__ rdeg_g,
        int* __restrict__ row_ptr, unsigned short* __restrict__ csr,
        unsigned short* __restrict__ hs, unsigned short* __restrict__ hinit,
        int n) {
    __shared__ int dl[256], cur[256];
    __shared__ int wsum4[4], pref4[4];
    __shared__ int total_s;
    __shared__ unsigned short stg[BCAP];
    int tid = threadIdx.x;
    int b   = blockIdx.x;
    if (tid < 256) dl[tid] = 0;
    __syncthreads();
    int cb = bcount[b];
    const unsigned int* __restrict__ bp = bucket + ((size_t)b << 13);
    for (int k = tid; k < cb; k += 512)
        atomicAdd(&dl[(bp[k] >> 16) & 255], 1);
    __syncthreads();
    int x = 0, val = 0;
    if (tid < 256) {                  // scan of 8-padded lengths
        x = (dl[tid] + 7) & ~7;
        val = x;
        int lane = tid & 63;
        #pragma unroll
        for (int off = 1; off < 64; off <<= 1) {
            int t = __shfl_up(val, off, 64);
            if (lane >= off) val += t;
        }
        if (lane == 63) wsum4[tid >> 6] = val;
    }
    __syncthreads();
    if (tid == 0) {
        int s = 0;
        #pragma unroll
        for (int w = 0; w < 4; ++w) { pref4[w] = s; s += wsum4[w]; }
        total_s = s;
    }
    __syncthreads();
    if (tid < 256) {
        int off_ex = val + pref4[tid >> 6] - x;     // padded exclusive offset
        cur[tid] = off_ex;
        int node = (b << BSH) + tid;
        if (node < n) {
            rdeg_g[node]  = dl[tid];
            row_ptr[node] = (b << 13) + off_ex;
        }
    }
    __syncthreads();
    int total = total_s;
    for (int k = tid; k < total; k += 512)          // sentinel padding
        stg[k] = (unsigned short)n;
    __syncthreads();
    for (int k = tid; k < cb; k += 512) {           // LDS scatter
        unsigned int u = bp[k];
        int p = atomicAdd(&cur[(u >> 16) & 255], 1);
        stg[p] = (unsigned short)(u & 0xFFFFu);
    }
    __syncthreads();
    unsigned short* __restrict__ cout = csr + ((size_t)b << 13);
    for (int k = tid; k < total; k += 512)          // coalesced write-out
        cout[k] = stg[k];
    // fused feature scaling for this bucket's nodes (dl stable since count)
    const float4* __restrict__ f4 = (const float4*)feat;
    for (int k = tid; k < 256 * NCHB; k += 512) {
        int lv = k / NCHB;
        int c  = k - lv * NCHB;
        int v  = (b << BSH) + lv;
        if (v >= n) break;                          // k monotonic per thread
        float d  = (float)(dl[lv] + 1);
        float s  = rsqrtf(d);
        float iv = 1.0f / d;
        int ci = v * NCHB + c;
        float4 fa = f4[(size_t)ci * 2];
        float4 fb = f4[(size_t)ci * 2 + 1];
        u16x8 o, oi;
        o[0] = f2bf(fa.x * s);  oi[0] = f2bf(fa.x * iv);
        o[1] = f2bf(fa.y * s);  oi[1] = f2bf(fa.y * iv);
        o[2] = f2bf(fa.z * s);  oi[2] = f2bf(fa.z * iv);
        o[3] = f2bf(fa.w * s);  oi[3] = f2bf(fa.w * iv);
        o[4] = f2bf(fb.x * s);  oi[4] = f2bf(fb.x * iv);
        o[5] = f2bf(fb.y * s);  oi[5] = f2bf(fb.y * iv);
        o[6] = f2bf(fb.z * s);  oi[6] = f2bf(fb.z * iv);
        o[7] = f2bf(fb.w * s);  oi[7] = f2bf(fb.w * iv);
        ((u16x8*)hs)[ci]    = o;
        ((u16x8*)hinit)[ci] = oi;
    }
}

// ---------------- propagation ----------------
// Thread = (node v, chunk c). Rows 8-padded & sentinel-filled: the inner loop
// is a uniform 8-block — one 16B u16x8 csr load per 8 gathers, no remainder.
// Accumulator seeded with own row (the appended self-loop).
//   h_new = (own + sum hs[s]) * ds + hinit[v],  ds = rsqrt(rdeg+1)
//   LAST=0: write bf16(h_new * ds);  LAST=1: write fp32 h_new.
template <int LAST>
__global__ void __launch_bounds__(256) k_prop(
        const unsigned short* __restrict__ hs, const int* __restrict__ row_ptr,
        const int* __restrict__ rdeg, const unsigned short* __restrict__ csr,
        const unsigned short* __restrict__ hinit,
        void* __restrict__ outp, int nt) {
    int t = blockIdx.x * blockDim.x + threadIdx.x;
    if (t >= nt) return;
    int v = t / NCHB;
    int c = t - v * NCHB;
    int beg = row_ptr[v];                       // multiple of 8
    int dv  = rdeg[v];
    int nit = (dv + 7) >> 3;                    // 8-blocks (padded)
    const u16x8* __restrict__ hs8  = (const u16x8*)hs;
    const u16x8* __restrict__ csr8 = (const u16x8*)csr + (beg >> 3);
    u16x8 own = hs8[t];                         // self-loop contribution
    float a0 = bf2f(own[0]), a1 = bf2f(own[1]);
    float a2 = bf2f(own[2]), a3 = bf2f(own[3]);
    float a4 = bf2f(own[4]), a5 = bf2f(own[5]);
    float a6 = bf2f(own[6]), a7 = bf2f(own[7]);

    #define ACC(HV) do { \
        a0 += bf2f((HV)[0]); a1 += bf2f((HV)[1]); \
        a2 += bf2f((HV)[2]); a3 += bf2f((HV)[3]); \
        a4 += bf2f((HV)[4]); a5 += bf2f((HV)[5]); \
        a6 += bf2f((HV)[6]); a7 += bf2f((HV)[7]); } while (0)

    for (int it = 0; it < nit; ++it) {
        u16x8 sv8 = csr8[it];                   // 8 neighbor indices, 1 load
        u16x8 h0 = hs8[(int)sv8[0] * NCHB + c];
        u16x8 h1 = hs8[(int)sv8[1] * NCHB + c];
        u16x8 h2 = hs8[(int)sv8[2] * NCHB + c];
        u16x8 h3 = hs8[(int)sv8[3] * NCHB + c];
        u16x8 h4 = hs8[(int)sv8[4] * NCHB + c];
        u16x8 h5 = hs8[(int)sv8[5] * NCHB + c];
        u16x8 h6 = hs8[(int)sv8[6] * NCHB + c];
        u16x8 h7 = hs8[(int)sv8[7] * NCHB + c];
        ACC(h0); ACC(h1); ACC(h2); ACC(h3);
        ACC(h4); ACC(h5); ACC(h6); ACC(h7);
    }
    #undef ACC

    float sv = rsqrtf((float)(dv + 1));
    u16x8 hi = ((const u16x8*)hinit)[t];
    float r0 = a0 * sv + bf2f(hi[0]);
    float r1 = a1 * sv + bf2f(hi[1]);
    float r2 = a2 * sv + bf2f(hi[2]);
    float r3 = a3 * sv + bf2f(hi[3]);
    float r4 = a4 * sv + bf2f(hi[4]);
    float r5 = a5 * sv + bf2f(hi[5]);
    float r6 = a6 * sv + bf2f(hi[6]);
    float r7 = a7 * sv + bf2f(hi[7]);
    if (LAST) {
        float4* o4 = (float4*)outp;
        o4[t * 2]     = make_float4(r0, r1, r2, r3);
        o4[t * 2 + 1] = make_float4(r4, r5, r6, r7);
    } else {
        u16x8 o;
        o[0] = f2bf(r0 * sv); o[1] = f2bf(r1 * sv);
        o[2] = f2bf(r2 * sv); o[3] = f2bf(r3 * sv);
        o[4] = f2bf(r4 * sv); o[5] = f2bf(r5 * sv);
        o[6] = f2bf(r6 * sv); o[7] = f2bf(r7 * sv);
        ((u16x8*)outp)[t] = o;
    }
}

// ---------------- launch ----------------

extern "C" void kernel_launch(void* const* d_in, const int* in_sizes, int n_in,
                              void* d_out, int out_size, void* d_ws, size_t ws_size,
                              hipStream_t stream) {
    const int*   src  = (const int*)d_in[0];
    const int*   dst  = (const int*)d_in[1];
    const float* feat = (const float*)d_in[2];
    const int E  = in_sizes[0];
    const int n  = in_sizes[2] / NDF;
    const int nr = E - n;              // random edges; appended self-loops implicit
    float* out = (float*)d_out;

    // workspace carve-up (256B aligned)
    char* p = (char*)d_ws;
    auto take = [&](size_t bytes) {
        char* r = p;
        p += (bytes + 255) & ~size_t(255);
        return r;
    };
    const int NBK = (n + 255) >> 8;    // dst-buckets of 256 nodes
    int* bcount          = (int*)take(256 * 4);
    int* row_ptr         = (int*)take((size_t)n * 4);
    int* rdeg            = (int*)take((size_t)n * 4);
    unsigned int* bucket = (unsigned int*)take((size_t)256 * BCAP * 4);
    unsigned short* csr  = (unsigned short*)take((size_t)256 * BCAP * 2);
    unsigned short* hsA   = (unsigned short*)take((size_t)(n + 1) * NDF * 2);
    unsigned short* hsB   = (unsigned short*)take((size_t)(n + 1) * NDF * 2);
    unsigned short* hinit = (unsigned short*)take((size_t)n * NDF * 2);
    (void)ws_size;

    const int nt = n * NCHB;
    const int bT = (nt + 255) / 256;
    const int bA = (nr + TILE - 1) / TILE;

    // build (3 launches): init -> bucket partition -> fused count/fill/scale
    k_binit <<<1, 256, 0, stream>>>(bcount, hsA, hsB, n);
    k_passA <<<bA, 512, 0, stream>>>(src, dst, nr, bcount, bucket);
    k_passBC<<<NBK, 512, 0, stream>>>(bcount, bucket, feat, rdeg, row_ptr,
                                      csr, hsA, hinit, n);

    // K = 3 propagation rounds (ping-pong hsA/hsB, final round writes d_out)
    k_prop<0><<<bT, 256, 0, stream>>>(hsA, row_ptr, rdeg, csr, hinit, hsB, nt);
    k_prop<0><<<bT, 256, 0, stream>>>(hsB, row_ptr, rdeg, csr, hinit, hsA, nt);
    k_prop<1><<<bT, 256, 0, stream>>>(hsA, row_ptr, rdeg, csr, hinit, out, nt);
}